// Round 1
// baseline (273.823 us; speedup 1.0000x reference)
//
#include <hip/hip_runtime.h>
#include <math.h>

#define H 128
#define S 8
#define BB 4   // batches per block in main kernel (one wave each)

__device__ __forceinline__ float wave_allreduce_sum(float v) {
    #pragma unroll
    for (int off = 32; off; off >>= 1) v += __shfl_xor(v, off, 64);
    return v;
}

// ---------------- prep: v1 = W @ sim_w[:H], v2 = W @ sim_w[H:], new_slot ----
// ws layout (floats): [0:128) v1 | [128:256) v2 | [256:1280) new_slot[S][H]
__global__ __launch_bounds__(128) void prep_kernel(
        const float* __restrict__ memory,
        const float* __restrict__ o_emb_w,
        const float* __restrict__ attn_W,
        const float* __restrict__ sim_w,
        const float* __restrict__ forget_w,
        const int*   __restrict__ o_rg_p,
        float* __restrict__ ws) {
    const int t = threadIdx.x;  // 0..127
    // v1[t], v2[t]: row-dot of attn_W row t against the two sim_w halves
    float a1 = 0.f, a2 = 0.f;
    const float* wrow = attn_W + t * H;
    #pragma unroll 4
    for (int j = 0; j < H; ++j) {
        float w = wrow[j];
        a1 += w * sim_w[j];
        a2 += w * sim_w[H + j];
    }
    ws[t]     = a1;
    ws[H + t] = a2;

    // forget gate for the written region
    __shared__ float red[9][H];
    __shared__ float gate[S];
    __shared__ float dow_s;
    const int o_rg = o_rg_p[0];
    const float* sel = memory + (size_t)o_rg * (S * H);
    red[0][t] = o_emb_w[t] * forget_w[t];
    #pragma unroll
    for (int s = 0; s < S; ++s) red[1 + s][t] = sel[s * H + t] * forget_w[H + t];
    __syncthreads();
    if (t < 9) {
        float sum = 0.f;
        for (int i = 0; i < H; ++i) sum += red[t][i];
        if (t == 0) dow_s = sum; else red[t][0] = sum;
    }
    __syncthreads();
    if (t < S) gate[t] = 1.f / (1.f + expf(-(dow_s + red[1 + t][0])));
    __syncthreads();
    #pragma unroll
    for (int s = 0; s < S; ++s) {
        float g = gate[s];
        ws[2 * H + s * H + t] = sel[s * H + t] * (1.f - g) + o_emb_w[t] * g;
    }
}

// ---------------- main: per-batch attention + fused output GEMM -------------
__global__ __launch_bounds__(256) void main_kernel(
        const float* __restrict__ memory,
        const float* __restrict__ o_emb_r,
        const float* __restrict__ attn_W,
        const float* __restrict__ sim_b,
        const int*   __restrict__ o_rg_p,
        const int*   __restrict__ d_rg,
        const float* __restrict__ ws,
        float* __restrict__ out) {
    __shared__ float wm_lds[BB][H];
    const int u  = threadIdx.x;
    const int wv = u >> 6;   // wave id 0..3 == batch-within-block
    const int L  = u & 63;   // lane; handles elements 2L, 2L+1
    const int b  = blockIdx.x * BB + wv;

    const int o_rg = o_rg_p[0];
    const int r    = d_rg[b];
    const float2* src = (r == o_rg)
        ? (const float2*)(ws + 2 * H)                       // new_slot
        : (const float2*)(memory + (size_t)r * (S * H));    // raw region

    float2 rows[S];
    #pragma unroll
    for (int s = 0; s < S; ++s) rows[s] = src[s * (H / 2) + L];

    const float2 vv1 = ((const float2*)ws)[L];
    const float2 vv2 = ((const float2*)(ws + H))[L];
    const float2 oe  = ((const float2*)o_emb_r)[(size_t)b * (H / 2) + L];

    const float qs = wave_allreduce_sum(oe.x * vv1.x + oe.y * vv1.y);
    float d2[S];
    #pragma unroll
    for (int s = 0; s < S; ++s)
        d2[s] = wave_allreduce_sum(rows[s].x * vv2.x + rows[s].y * vv2.y);

    // relu logits + softmax over S (redundant per-lane, S=8 scalars)
    const float sb = sim_b[0];
    float l[S], m = -INFINITY;
    #pragma unroll
    for (int s = 0; s < S; ++s) { l[s] = fmaxf(qs + d2[s] + sb, 0.f); m = fmaxf(m, l[s]); }
    float p[S], psum = 0.f;
    #pragma unroll
    for (int s = 0; s < S; ++s) { p[s] = expf(l[s] - m); psum += p[s]; }
    const float inv = 1.f / psum;

    float2 wm = {0.f, 0.f};
    #pragma unroll
    for (int s = 0; s < S; ++s) {
        float ps = p[s] * inv;
        wm.x += ps * rows[s].x;
        wm.y += ps * rows[s].y;
    }
    wm_lds[wv][2 * L]     = wm.x;
    wm_lds[wv][2 * L + 1] = wm.y;
    __syncthreads();

    // out[b] = wm[b] @ attn_W. Thread (wv, L) computes cols 2L, 2L+1 of batch wv.
    // All 4 waves stream identical W addresses -> L1 broadcast; 64 KB/block L1 fill.
    const float2* W2 = (const float2*)attn_W;
    const float* wmrow = wm_lds[wv];
    float2 acc = {0.f, 0.f};
    #pragma unroll 4
    for (int i = 0; i < H; ++i) {
        float2 w  = W2[i * (H / 2) + L];
        float  wv_ = wmrow[i];
        acc.x += wv_ * w.x;
        acc.y += wv_ * w.y;
    }
    ((float2*)out)[(size_t)b * (H / 2) + L] = acc;
}

extern "C" void kernel_launch(void* const* d_in, const int* in_sizes, int n_in,
                              void* d_out, int out_size, void* d_ws, size_t ws_size,
                              hipStream_t stream) {
    const float* memory   = (const float*)d_in[0];  // [R,S,H]
    const float* o_emb_w  = (const float*)d_in[1];  // [H]
    const float* o_emb_r  = (const float*)d_in[2];  // [B,H]
    const float* attn_W   = (const float*)d_in[3];  // [H,H]
    const float* sim_w    = (const float*)d_in[4];  // [2H,1]
    const float* sim_b    = (const float*)d_in[5];  // [1]
    const float* forget_w = (const float*)d_in[6];  // [2H,1]
    const int*   o_rg     = (const int*)d_in[7];    // scalar
    const int*   d_rg     = (const int*)d_in[8];    // [B]
    float* out = (float*)d_out;
    float* ws  = (float*)d_ws;

    const int B = in_sizes[8];  // 4096

    prep_kernel<<<1, 128, 0, stream>>>(memory, o_emb_w, attn_W, sim_w, forget_w, o_rg, ws);
    main_kernel<<<B / BB, 256, 0, stream>>>(memory, o_emb_r, attn_W, sim_b, o_rg, d_rg, ws, out);
}

// Round 2
// 271.652 us; speedup vs baseline: 1.0080x; 1.0080x over previous
//
#include <hip/hip_runtime.h>
#include <math.h>

#define H  128
#define S  8
#define BB 4   // batches per block, one wave each

__device__ __forceinline__ float wave_sum(float v) {
    #pragma unroll
    for (int off = 32; off; off >>= 1) v += __shfl_xor(v, off, 64);
    return v;
}

// Single fused kernel.
//  - per-block (redundant, cheap): v1 = attn_W @ sim_w[:H], v2 = attn_W @ sim_w[H:]
//  - per-wave: gather region, (rare) forget-gate fix when r==o_rg, qs/d2 shuffle
//    reductions, softmax over S=8, weighted slot mix wm
//  - per-block epilogue: out[b] = wm[b] @ attn_W (W is L1-hot from v1/v2 pass)
__global__ __launch_bounds__(256) void fused_kernel(
        const float* __restrict__ memory,    // [R,S,H]
        const float* __restrict__ o_emb_w,   // [H]
        const float* __restrict__ o_emb_r,   // [B,H]
        const float* __restrict__ attn_W,    // [H,H]
        const float* __restrict__ sim_w,     // [2H]
        const float* __restrict__ sim_b,     // [1]
        const float* __restrict__ forget_w,  // [2H]
        const int*   __restrict__ o_rg_p,
        const int*   __restrict__ d_rg,      // [B]
        float* __restrict__ out) {           // [B,H]
    __shared__ float v1s[H], v2s[H];
    __shared__ float wm_lds[BB][H];

    const int u  = threadIdx.x;
    const int wv = u >> 6;   // wave id == batch-within-block
    const int L  = u & 63;   // lane; handles elements 2L, 2L+1
    const int b  = blockIdx.x * BB + wv;

    const int o_rg = o_rg_p[0];
    const int r    = d_rg[b];

    // ---- issue the latency-heavy gather first (4 KB contiguous per wave) ----
    const float2* src = (const float2*)(memory + (size_t)r * (S * H));
    float2 rows[S];
    #pragma unroll
    for (int s = 0; s < S; ++s) rows[s] = src[s * (H / 2) + L];
    const float2 oe = ((const float2*)o_emb_r)[(size_t)b * (H / 2) + L];

    // ---- per-block v1/v2: thread t -> row (t&127), half (t>>7) ----
    {
        const int row = u & 127, half = u >> 7;
        const float2* wr = (const float2*)(attn_W + row * H + half * 64);
        const float2* s1 = (const float2*)(sim_w + half * 64);
        const float2* s2 = (const float2*)(sim_w + H + half * 64);
        float a1 = 0.f, a2 = 0.f;
        #pragma unroll 8
        for (int j = 0; j < 32; ++j) {
            float2 w = wr[j], x1 = s1[j], x2 = s2[j];
            a1 += w.x * x1.x + w.y * x1.y;
            a2 += w.x * x2.x + w.y * x2.y;
        }
        if (half == 0) { v1s[row] = a1; v2s[row] = a2; }
        __syncthreads();
        if (half == 1) { v1s[row] += a1; v2s[row] += a2; }
        __syncthreads();
    }

    // ---- rare: this wave's region is the written one -> apply forget gate ----
    if (r == o_rg) {
        const float2 ow = ((const float2*)o_emb_w)[L];
        const float2 f1 = ((const float2*)forget_w)[L];
        const float2 f2 = ((const float2*)(forget_w + H))[L];
        const float base = wave_sum(ow.x * f1.x + ow.y * f1.y);
        #pragma unroll
        for (int s = 0; s < S; ++s) {
            float d = wave_sum(rows[s].x * f2.x + rows[s].y * f2.y);
            float g = 1.f / (1.f + expf(-(base + d)));
            rows[s].x = rows[s].x * (1.f - g) + ow.x * g;
            rows[s].y = rows[s].y * (1.f - g) + ow.y * g;
        }
    }

    // ---- attention logits via v1/v2 ----
    const float2 vv1 = ((const float2*)v1s)[L];
    const float2 vv2 = ((const float2*)v2s)[L];
    const float qs = wave_sum(oe.x * vv1.x + oe.y * vv1.y);
    float d2[S];
    #pragma unroll
    for (int s = 0; s < S; ++s)
        d2[s] = wave_sum(rows[s].x * vv2.x + rows[s].y * vv2.y);

    // softmax over S (redundant per-lane, 8 scalars)
    const float sb = sim_b[0];
    float l[S], m = -INFINITY;
    #pragma unroll
    for (int s = 0; s < S; ++s) { l[s] = fmaxf(qs + d2[s] + sb, 0.f); m = fmaxf(m, l[s]); }
    float p[S], psum = 0.f;
    #pragma unroll
    for (int s = 0; s < S; ++s) { p[s] = expf(l[s] - m); psum += p[s]; }
    const float inv = 1.f / psum;

    float2 wm = {0.f, 0.f};
    #pragma unroll
    for (int s = 0; s < S; ++s) {
        float ps = p[s] * inv;
        wm.x += ps * rows[s].x;
        wm.y += ps * rows[s].y;
    }
    wm_lds[wv][2 * L]     = wm.x;
    wm_lds[wv][2 * L + 1] = wm.y;
    __syncthreads();

    // ---- epilogue: out[b] = wm[b] @ attn_W; thread (wv,L) -> cols 2L,2L+1 ----
    const float2* W2 = (const float2*)attn_W;
    const float* wmrow = wm_lds[wv];
    float2 acc = {0.f, 0.f};
    #pragma unroll 4
    for (int i = 0; i < H; ++i) {
        float2 w = W2[i * (H / 2) + L];
        float  x = wmrow[i];
        acc.x += x * w.x;
        acc.y += x * w.y;
    }
    ((float2*)out)[(size_t)b * (H / 2) + L] = acc;
}

extern "C" void kernel_launch(void* const* d_in, const int* in_sizes, int n_in,
                              void* d_out, int out_size, void* d_ws, size_t ws_size,
                              hipStream_t stream) {
    const float* memory   = (const float*)d_in[0];
    const float* o_emb_w  = (const float*)d_in[1];
    const float* o_emb_r  = (const float*)d_in[2];
    const float* attn_W   = (const float*)d_in[3];
    const float* sim_w    = (const float*)d_in[4];
    const float* sim_b    = (const float*)d_in[5];
    const float* forget_w = (const float*)d_in[6];
    const int*   o_rg     = (const int*)d_in[7];
    const int*   d_rg     = (const int*)d_in[8];
    float* out = (float*)d_out;

    const int B = in_sizes[8];  // 4096

    fused_kernel<<<B / BB, 256, 0, stream>>>(
        memory, o_emb_w, o_emb_r, attn_W, sim_w, sim_b, forget_w, o_rg, d_rg, out);
}

// Round 3
// 264.584 us; speedup vs baseline: 1.0349x; 1.0267x over previous
//
#include <hip/hip_runtime.h>
#include <math.h>

#define H  128
#define S  8
#define BB 8   // batches per block, one wave each (512-thread blocks)

__device__ __forceinline__ float wave_sum(float v) {
    #pragma unroll
    for (int off = 32; off; off >>= 1) v += __shfl_xor(v, off, 64);
    return v;
}

// Single fused kernel, half-wave slot layout:
//   gather: 4 x dwordx4 per lane covers all 8 slots (lanes 0-31 = even slot,
//   32-63 = odd slot of each pair). Reductions: 5-step butterfly within the
//   half-wave + one xor-32 to share across halves.
__global__ __launch_bounds__(512) void fused_kernel(
        const float* __restrict__ memory,    // [R,S,H]
        const float* __restrict__ o_emb_w,   // [H]
        const float* __restrict__ o_emb_r,   // [B,H]
        const float* __restrict__ attn_W,    // [H,H]
        const float* __restrict__ sim_w,     // [2H]
        const float* __restrict__ sim_b,     // [1]
        const float* __restrict__ forget_w,  // [2H]
        const int*   __restrict__ o_rg_p,
        const int*   __restrict__ d_rg,      // [B]
        float* __restrict__ out) {           // [B,H]
    __shared__ float v1s[H], v2s[H];
    __shared__ float wm_lds[BB][H];

    const int u  = threadIdx.x;
    const int wv = u >> 6;     // wave id == batch-within-block (0..7)
    const int L  = u & 63;
    const int c  = L & 31;     // float4 column index
    const int hi = L >> 5;     // 0 = even slots, 1 = odd slots
    const int b  = blockIdx.x * BB + wv;

    const int o_rg = o_rg_p[0];
    const int r    = d_rg[b];

    // ---- gather first (latency-heavy): 4 x 16B loads = whole 4 KB region ----
    // load j: float4 idx 64j+L -> lanes 0-31 slot 2j (elems 4c..), 32-63 slot 2j+1
    const float4* src4 = (const float4*)(memory + (size_t)r * (S * H));
    float4 rows[4];
    #pragma unroll
    for (int j = 0; j < 4; ++j) rows[j] = src4[j * 64 + L];
    const float2 oe = ((const float2*)o_emb_r)[(size_t)b * (H / 2) + L];

    // ---- v1 = attn_W @ sim_w[:H], v2 = attn_W @ sim_w[H:], threads 0..255 ----
    if (u < 256) {
        const int row = u & 127;
        const float4* wr = (const float4*)(attn_W + row * H);
        const float4* sv = (const float4*)(sim_w + (u >> 7) * H);
        float a = 0.f;
        #pragma unroll 8
        for (int j = 0; j < 32; ++j) {
            float4 w = wr[j], x = sv[j];
            a += w.x * x.x + w.y * x.y + w.z * x.z + w.w * x.w;
        }
        if (u < 128) v1s[row] = a; else v2s[row] = a;
    }
    __syncthreads();

    // ---- rare: this wave's region is the written one -> forget-gate fix ----
    if (r == o_rg) {
        const float4 ow4 = ((const float4*)o_emb_w)[c];
        const float4 f24 = ((const float4*)(forget_w + H))[c];
        const float2 ow2 = ((const float2*)o_emb_w)[L];
        const float2 f12 = ((const float2*)forget_w)[L];
        const float base = wave_sum(ow2.x * f12.x + ow2.y * f12.y);
        #pragma unroll
        for (int j = 0; j < 4; ++j) {
            float v = rows[j].x * f24.x + rows[j].y * f24.y
                    + rows[j].z * f24.z + rows[j].w * f24.w;
            #pragma unroll
            for (int off = 1; off <= 16; off <<= 1) v += __shfl_xor(v, off, 64);
            // v is now this half-wave's slot sum; gate applies to own slot only
            float g = 1.f / (1.f + expf(-(base + v)));
            rows[j].x = rows[j].x * (1.f - g) + ow4.x * g;
            rows[j].y = rows[j].y * (1.f - g) + ow4.y * g;
            rows[j].z = rows[j].z * (1.f - g) + ow4.z * g;
            rows[j].w = rows[j].w * (1.f - g) + ow4.w * g;
        }
    }

    // ---- attention logits ----
    const float2 vv1 = ((const float2*)v1s)[L];
    const float  qs  = wave_sum(oe.x * vv1.x + oe.y * vv1.y);
    const float4 vv2 = ((const float4*)v2s)[c];

    float d2own[4], d2oth[4];   // own-half slot order; softmax is order-invariant
    #pragma unroll
    for (int j = 0; j < 4; ++j) {
        float v = rows[j].x * vv2.x + rows[j].y * vv2.y
                + rows[j].z * vv2.z + rows[j].w * vv2.w;
        #pragma unroll
        for (int off = 1; off <= 16; off <<= 1) v += __shfl_xor(v, off, 64);
        d2own[j] = v;
        d2oth[j] = __shfl_xor(v, 32, 64);
    }

    const float sb = sim_b[0];
    float lown[4], loth[4], m = -INFINITY;
    #pragma unroll
    for (int j = 0; j < 4; ++j) {
        lown[j] = fmaxf(qs + d2own[j] + sb, 0.f);
        loth[j] = fmaxf(qs + d2oth[j] + sb, 0.f);
        m = fmaxf(m, fmaxf(lown[j], loth[j]));
    }
    float pown[4], psum = 0.f;
    #pragma unroll
    for (int j = 0; j < 4; ++j) {
        pown[j] = expf(lown[j] - m);
        psum += pown[j] + expf(loth[j] - m);
    }
    const float inv = 1.f / psum;

    // weighted slot mix: own-half slots only, then combine halves
    float4 wm = {0.f, 0.f, 0.f, 0.f};
    #pragma unroll
    for (int j = 0; j < 4; ++j) {
        float ps = pown[j] * inv;
        wm.x += ps * rows[j].x;
        wm.y += ps * rows[j].y;
        wm.z += ps * rows[j].z;
        wm.w += ps * rows[j].w;
    }
    wm.x += __shfl_xor(wm.x, 32, 64);
    wm.y += __shfl_xor(wm.y, 32, 64);
    wm.z += __shfl_xor(wm.z, 32, 64);
    wm.w += __shfl_xor(wm.w, 32, 64);
    if (hi == 0) ((float4*)wm_lds[wv])[c] = wm;
    __syncthreads();

    // ---- epilogue: out[b] = wm[b] @ attn_W, split-K across lane halves ----
    const float4* W4 = (const float4*)attn_W;
    const float* wmrow = wm_lds[wv];
    float4 acc = {0.f, 0.f, 0.f, 0.f};
    #pragma unroll 8
    for (int j = 0; j < 64; ++j) {
        int i = hi * 64 + j;
        float4 w = W4[i * (H / 4) + c];
        float  x = wmrow[i];              // 2-addr LDS broadcast (free 2-way)
        acc.x += x * w.x;
        acc.y += x * w.y;
        acc.z += x * w.z;
        acc.w += x * w.w;
    }
    acc.x += __shfl_xor(acc.x, 32, 64);
    acc.y += __shfl_xor(acc.y, 32, 64);
    acc.z += __shfl_xor(acc.z, 32, 64);
    acc.w += __shfl_xor(acc.w, 32, 64);
    if (hi == 0) ((float4*)out)[(size_t)b * (H / 4) + c] = acc;
}

extern "C" void kernel_launch(void* const* d_in, const int* in_sizes, int n_in,
                              void* d_out, int out_size, void* d_ws, size_t ws_size,
                              hipStream_t stream) {
    const float* memory   = (const float*)d_in[0];
    const float* o_emb_w  = (const float*)d_in[1];
    const float* o_emb_r  = (const float*)d_in[2];
    const float* attn_W   = (const float*)d_in[3];
    const float* sim_w    = (const float*)d_in[4];
    const float* sim_b    = (const float*)d_in[5];
    const float* forget_w = (const float*)d_in[6];
    const int*   o_rg     = (const int*)d_in[7];
    const int*   d_rg     = (const int*)d_in[8];
    float* out = (float*)d_out;

    const int B = in_sizes[8];  // 4096

    fused_kernel<<<B / BB, 512, 0, stream>>>(
        memory, o_emb_w, o_emb_r, attn_W, sim_w, sim_b, forget_w, o_rg, d_rg, out);
}